// Round 13
// baseline (329.663 us; speedup 1.0000x reference)
//
#include <hip/hip_runtime.h>

typedef unsigned int u32;
typedef unsigned long long u64;

#define C_DIM 256
#define HW 1024
#define N_TOT 16384
#define K_DIM 8192
#define ZQ_SIZE 4194304
#define LOSS_OFF ZQ_SIZE
#define IDX_OFF (ZQ_SIZE + 1)

#define KRANGE 2048
#define MARGIN 8.0f
#define CAP 524288u
#define LCAP 4096u

// workspace offsets (floats)
#define WS_ENORM 0          // 8192 (stores ||e||^2 + 1024)
#define WS_CNT 8192         // 1 u32
#define WS_PACKED 16384     // 16384 u64 = 32768 f
#define WS_FIDX 49152       // 16384
#define WS_LPART 65536      // 2048
#define WS_LIST 131072      // CAP uint2 = 1048576 f
#define WS_ZT32 1179648     // 4194304
#define WS_ZT8 5373952      // 16384*256 fp8 = 1048576 f
#define WS_EB8 6422528      // 8192*256 fp8 = 524288 f -> ends 6946816 f = 27.8 MB

typedef __attribute__((ext_vector_type(4))) float f32x4;
typedef __attribute__((ext_vector_type(2))) long i64x2;

__device__ __forceinline__ void gld_lds16(const void* g, void* l) {
    __builtin_amdgcn_global_load_lds(
        (const __attribute__((address_space(1))) u32*)g,
        (__attribute__((address_space(3))) u32*)l, 16, 0, 0);
}

// fp32 -> OCP e4m3fn, RNE, clamp to +-448 (never emits NaN code 0x7F)
__device__ __forceinline__ u32 f2e4m3(float x) {
    u32 b = __float_as_uint(x);
    u32 s = (b >> 24) & 0x80u;
    float a = __uint_as_float(b & 0x7FFFFFFFu);
    if (a >= 464.0f) return s | 0x7Eu;          // clamp to 448
    if (a < 0.015625f) {                         // subnormal: ulp 2^-9
        int q = __float2int_rn(a * 512.0f);      // 0..8 (8 == 2^-6 -> code 0x08)
        return s | (u32)q;
    }
    u32 m = b & 0x7FFFFFFFu;
    m += 0x7FFFFu + ((m >> 20) & 1u);            // RNE into bit 20 (carry-safe)
    u32 e = ((m >> 23) & 0xFFu) - 127u + 7u;
    return s | (e << 3) | ((m >> 20) & 7u);
}

// C-permutation: p(c) groups each lane's two consecutive K-window octets contiguously.
// p = (c>>6)*64 + ((c>>3)&3)*16 + ((c>>5)&1)*8 + (c&7). Applied to BOTH z and e.

// ---------------- prep e: fp8 codebook (permuted) + (||e||^2 + 1024) ----------------
__global__ __launch_bounds__(256) void k_prep_e(const float* __restrict__ e,
                                                unsigned char* __restrict__ eb8,
                                                float* __restrict__ enorm1) {
    int w = threadIdx.x >> 6, l = threadIdx.x & 63;
    int row = blockIdx.x * 4 + w;
    const float4 v = *reinterpret_cast<const float4*>(e + (size_t)row * C_DIM + l * 4);
    float s = v.x * v.x + v.y * v.y + v.z * v.z + v.w * v.w;
    #pragma unroll
    for (int off = 32; off; off >>= 1) s += __shfl_xor(s, off, 64);
    if (l == 0) enorm1[row] = s + 1024.0f;
    // c0 = 4*l; permuted dest (4B-aligned run of 4)
    int p = ((l >> 4) << 6) + (((l >> 1) & 3) << 4) + (((l >> 3) & 1) << 3) + ((l & 1) << 2);
    u32 pk = f2e4m3(v.x) | (f2e4m3(v.y) << 8) | (f2e4m3(v.z) << 16) | (f2e4m3(v.w) << 24);
    *reinterpret_cast<u32*>(eb8 + (size_t)row * C_DIM + p) = pk;
}

// ---------------- prep z: transpose to [n][c] fp32 + permuted fp8 ----------------
__global__ __launch_bounds__(256) void k_prep_z(const float* __restrict__ z,
                                                float* __restrict__ zt32,
                                                unsigned char* __restrict__ zt8) {
    int bid = blockIdx.x;
    int b = bid >> 7;
    int hwt = (bid >> 3) & 15;
    int ct = bid & 7;
    int t = threadIdx.x;
    __shared__ float tile[32][65];
    #pragma unroll
    for (int p = 0; p < 8; ++p) {
        int cl = p * 4 + (t >> 6), hl = t & 63;
        tile[cl][hl] = z[((size_t)b << 18) + ((size_t)(ct * 32 + cl) << 10) + hwt * 64 + hl];
    }
    __syncthreads();
    int hl = t & 63, cg = t >> 6;
    int n = (b << 10) + hwt * 64 + hl;
    float v[8];
    #pragma unroll
    for (int j = 0; j < 8; ++j) v[j] = tile[cg * 8 + j][hl];
    size_t base = (size_t)n * C_DIM + ct * 32 + cg * 8;
    *reinterpret_cast<float4*>(zt32 + base) = make_float4(v[0], v[1], v[2], v[3]);
    *reinterpret_cast<float4*>(zt32 + base + 4) = make_float4(v[4], v[5], v[6], v[7]);
    // fp8 permuted: c0 = ct*32 + cg*8 -> p0 = (ct>>1)*64 + cg*16 + (ct&1)*8 (8B-aligned run)
    u64 pk = 0;
    #pragma unroll
    for (int j = 0; j < 8; ++j) pk |= (u64)f2e4m3(v[j]) << (8 * j);
    int p0 = ((ct >> 1) << 6) + (cg << 4) + ((ct & 1) << 3);
    *reinterpret_cast<u64*>(zt8 + (size_t)n * C_DIM + p0) = pk;
}

// ---------------- fp8 MFMA screen: A 32KB LDS, B dbuf 2x4KB... (2x8KB windows), 3 blocks/CU ----------------
__global__ __launch_bounds__(256, 2) void k_screen(const unsigned char* __restrict__ zt8,
                                                   const unsigned char* __restrict__ eb8,
                                                   const float* __restrict__ enorm1,
                                                   u32* __restrict__ cnt,
                                                   uint2* __restrict__ list) {
    // LDS: A 32KB | B 2x8KB | scratch; cbuf reuses A post-loop. 50696B -> ~3 blocks/CU
    __shared__ __align__(16) char lds[50704];
    char* Ab = lds;
    char* Bb = lds + 32768;

    int logical = (blockIdx.x & 7) * 64 + (blockIdx.x >> 3);   // bijective, XCD-grouped
    const int ks = logical >> 7;
    const int rowtile = logical & 127;
    const int n0 = rowtile * 128;
    const int kbase = ks * KRANGE;

    const int tid = threadIdx.x;
    const int l = tid & 63, w = tid >> 6;
    const int wr = w >> 1, wc = w & 1;
    const int ll = l & 15, lh = l >> 4;

    // ---- stage A once: 128 rows x 256B fp8 (inverse-swizzled source, linear dest) ----
    #pragma unroll
    for (int j = 0; j < 8; ++j) {
        int unit = (w * 8 + j) * 64 + l;          // 16B units
        int row = unit >> 4;
        int slot = unit & 15;
        const char* src = (const char*)zt8 + (((size_t)(n0 + row)) << 8)
                          + ((slot ^ (row & 15)) << 4);
        gld_lds16(src, Ab + (w * 8 + j) * 1024);
    }

    // ---- B stage constants: window chunk = 128 krows x 64B = 8KB; 2 instrs/wave ----
    const char* srcB[2];
    char* dstB[2];
    #pragma unroll
    for (int j = 0; j < 2; ++j) {
        int unit = j * 256 + w * 64 + l;           // 16B units in 8KB
        int rB = unit >> 2;
        int sB = unit & 3;
        int sw = (rB ^ (rB >> 2)) & 3;
        srcB[j] = (const char*)eb8 + ((size_t)(kbase + rB) << 8) + ((sB ^ sw) << 4);
        dstB[j] = Bb + (j * 256 + w * 64) * 16;
    }

    // A read offsets (row constant per mf)
    int aoff[4], rxA[4];
    #pragma unroll
    for (int mf = 0; mf < 4; ++mf) {
        int row = wr * 64 + mf * 16 + ll;
        aoff[mf] = row * 256;
        rxA[mf] = row & 15;
    }
    // B read offsets (constant per kf)
    int bfrOff[4];
    #pragma unroll
    for (int kf = 0; kf < 4; ++kf) {
        int row = wc * 64 + kf * 16 + ll;
        int sw = (row ^ (row >> 2)) & 3;
        bfrOff[kf] = row * 64 + ((lh ^ sw) << 4);
    }

    f32x4 acc[4][4];
    #pragma unroll
    for (int a = 0; a < 4; ++a)
        #pragma unroll
        for (int b = 0; b < 4; ++b) acc[a][b] = (f32x4){0.f, 0.f, 0.f, 0.f};
    float m1[16], m2[16];
    #pragma unroll
    for (int s = 0; s < 16; ++s) { m1[s] = 3.4e38f; m2[s] = 3.4e38f; }

    // prologue: stage window 0 into buf0
    gld_lds16(srcB[0], dstB[0]);
    gld_lds16(srcB[1], dstB[1]);
    __syncthreads();

    for (int it = 0; it < 16; ++it) {
        float en[4];
        #pragma unroll
        for (int kf = 0; kf < 4; ++kf)
            en[kf] = enorm1[kbase + it * 128 + wc * 64 + kf * 16 + ll];

        #pragma unroll
        for (int t = 0; t < 4; ++t) {
            const int p = t & 1;                   // it*4+t parity == t parity (4 windows/it)
            // stage next window into the other buffer (issue-early)
            if (it < 15 || t < 3) {
                const int nw = it * 4 + t + 1;
                const size_t koff = (size_t)(nw >> 2) * 32768 + (size_t)((nw & 3) * 64);
                gld_lds16(srcB[0] + koff, dstB[0] + (p ^ 1) * 8192);
                gld_lds16(srcB[1] + koff, dstB[1] + (p ^ 1) * 8192);
            }
            // fragments: one b128 per operand per frag = BOTH K-sub-steps
            i64x2 av[4], bv[4];
            #pragma unroll
            for (int mf = 0; mf < 4; ++mf)
                av[mf] = *reinterpret_cast<const i64x2*>(
                    Ab + aoff[mf] + (((t * 4 + lh) ^ rxA[mf]) << 4));
            #pragma unroll
            for (int kf = 0; kf < 4; ++kf)
                bv[kf] = *reinterpret_cast<const i64x2*>(Bb + p * 8192 + bfrOff[kf]);
            __builtin_amdgcn_s_setprio(1);
            #pragma unroll
            for (int mf = 0; mf < 4; ++mf)
                #pragma unroll
                for (int kf = 0; kf < 4; ++kf)
                    acc[mf][kf] = __builtin_amdgcn_mfma_f32_16x16x32_fp8_fp8(
                        av[mf].x, bv[kf].x, acc[mf][kf], 0, 0, 0);
            #pragma unroll
            for (int mf = 0; mf < 4; ++mf)
                #pragma unroll
                for (int kf = 0; kf < 4; ++kf)
                    acc[mf][kf] = __builtin_amdgcn_mfma_f32_16x16x32_fp8_fp8(
                        av[mf].y, bv[kf].y, acc[mf][kf], 0, 0, 0);
            __builtin_amdgcn_s_setprio(0);

            if (t == 3) {
                // epilogue: packed (d,k) top-2 update; d = en' - 2*dot
                #pragma unroll
                for (int kf = 0; kf < 4; ++kf) {
                    const u32 kcol = (u32)(kbase + it * 128 + wc * 64 + kf * 16 + ll);
                    #pragma unroll
                    for (int mf = 0; mf < 4; ++mf) {
                        #pragma unroll
                        for (int r = 0; r < 4; ++r) {
                            float d = fmaf(-2.0f, acc[mf][kf][r], en[kf]);
                            float df = __uint_as_float((__float_as_uint(d) & 0xFFFFE000u) | kcol);
                            const int s2 = mf * 4 + r;
                            float tt = fmaxf(m1[s2], df);
                            m2[s2] = fminf(m2[s2], tt);
                            m1[s2] = fminf(m1[s2], df);
                            acc[mf][kf][r] = 0.0f;
                        }
                    }
                }
            }
            __syncthreads();
        }
    }

    // ---- row-split min via butterfly on a COPY (per-thread m1/m2 preserved) ----
    float rowm[16];
    #pragma unroll
    for (int s = 0; s < 16; ++s) rowm[s] = m1[s];
    #pragma unroll
    for (int m = 1; m <= 8; m <<= 1)
        #pragma unroll
        for (int s = 0; s < 16; ++s)
            rowm[s] = fminf(rowm[s], __shfl_xor(rowm[s], m, 64));

    // LDS scratch (tail region; cbuf reuses A region after barriers)
    float* LDSrm = (float*)(lds + 49152);    // [128][2]
    float* LDSrmF = (float*)(lds + 50176);   // [128]
    u32* ccnt = (u32*)(lds + 50688);
    u32* gbase = (u32*)(lds + 50692);
    uint2* cbuf = (uint2*)lds;               // 4096 entries (32KB)

    if (ll == 0) {
        #pragma unroll
        for (int s = 0; s < 16; ++s) {
            int row_local = wr * 64 + (s >> 2) * 16 + lh * 4 + (s & 3);
            LDSrm[row_local * 2 + wc] = rowm[s];
        }
    }
    if (tid == 0) *ccnt = 0;
    __syncthreads();
    if (tid < 128)
        LDSrmF[tid] = fminf(LDSrm[tid * 2], LDSrm[tid * 2 + 1]);
    __syncthreads();

    // ---- emission (per-thread bests; block-compacted) ----
    #pragma unroll
    for (int s = 0; s < 16; ++s) {
        int row_local = wr * 64 + (s >> 2) * 16 + lh * 4 + (s & 3);
        float rm = __uint_as_float(__float_as_uint(LDSrmF[row_local]) & 0xFFFFE000u);
        float d1 = __uint_as_float(__float_as_uint(m1[s]) & 0xFFFFE000u);
        if (d1 <= rm + MARGIN) {
            u32 pos = atomicAdd(ccnt, 1u);
            uint2 ent = make_uint2((u32)(n0 + row_local), __float_as_uint(m1[s]) & 8191u);
            if (pos < LCAP) cbuf[pos] = ent;
            else { u32 gp = atomicAdd(cnt, 1u); if (gp < CAP) list[gp] = ent; }
        }
        float d2 = __uint_as_float(__float_as_uint(m2[s]) & 0xFFFFE000u);
        if (d2 <= rm + MARGIN) {
            // rare: a 3rd candidate may hide in this thread-slot's 64-k subset -> emit all
            for (int it2 = 0; it2 < 16; ++it2) {
                #pragma unroll
                for (int kf = 0; kf < 4; ++kf) {
                    u32 k = (u32)(kbase + it2 * 128 + wc * 64 + kf * 16 + ll);
                    u32 pos = atomicAdd(ccnt, 1u);
                    uint2 ent = make_uint2((u32)(n0 + row_local), k);
                    if (pos < LCAP) cbuf[pos] = ent;
                    else { u32 gp = atomicAdd(cnt, 1u); if (gp < CAP) list[gp] = ent; }
                }
            }
        }
    }
    __syncthreads();
    if (tid == 0) {
        u32 total = *ccnt; if (total > LCAP) total = LCAP;
        *gbase = atomicAdd(cnt, total);
    }
    __syncthreads();
    u32 total = *ccnt; if (total > LCAP) total = LCAP;
    u32 gb = *gbase;
    for (u32 i = tid; i < total; i += 256) {
        u32 gp = gb + i;
        if (gp < CAP) list[gp] = cbuf[i];
    }
}

// ---------------- exact fp32 recheck of candidates ----------------
__global__ __launch_bounds__(256) void k_exact(const float* __restrict__ zt32,
                                               const float* __restrict__ e,
                                               const float* __restrict__ enorm1,
                                               const u32* __restrict__ cnt,
                                               const uint2* __restrict__ list,
                                               u64* __restrict__ packed) {
    const int nw = gridDim.x * 4;
    const int wid = blockIdx.x * 4 + (threadIdx.x >> 6);
    const int l = threadIdx.x & 63;
    u32 total = *cnt;
    if (total > CAP) total = CAP;
    for (u32 i = wid; i < total; i += nw) {
        uint2 c = list[i];
        const float4 zv = *reinterpret_cast<const float4*>(zt32 + (size_t)c.x * C_DIM + l * 4);
        const float4 ev = *reinterpret_cast<const float4*>(e + (size_t)c.y * C_DIM + l * 4);
        float s = zv.x * ev.x + zv.y * ev.y + zv.z * ev.z + zv.w * ev.w;
        #pragma unroll
        for (int off = 32; off; off >>= 1) s += __shfl_xor(s, off, 64);
        if (l == 0) {
            float d = fmaf(-2.0f, s, enorm1[c.y]);   // +1024 shift uniform: order preserved
            u32 ub = __float_as_uint(d);
            ub = (ub & 0x80000000u) ? ~ub : (ub | 0x80000000u);
            u64 key = ((u64)ub << 32) | (u64)c.y;
            atomicMin(packed + c.x, key);
        }
    }
}

// ---------------- finalize indices (clamped: never fault downstream) ----------------
__global__ __launch_bounds__(256) void k_fin(const u64* __restrict__ packed,
                                             int* __restrict__ fidx,
                                             float* __restrict__ out_idx) {
    int n = blockIdx.x * 256 + threadIdx.x;
    if (n >= N_TOT) return;
    u32 kk = (u32)(packed[n] & 0xFFFFFFFFull);
    if (kk > 8191u) kk = 0u;   // safety net: visible wrong answer instead of GPU fault
    fidx[n] = (int)kk;
    out_idx[n] = (float)kk;
}

// ---------------- gather z_q + loss partials ----------------
#define GBLOCKS 2048
__global__ __launch_bounds__(256) void k_gather(const float* __restrict__ z,
                                                const float* __restrict__ e,
                                                const int* __restrict__ fidx,
                                                float* __restrict__ zq,
                                                float* __restrict__ lpart) {
    float s = 0.0f;
    for (int i = blockIdx.x * 256 + threadIdx.x; i < ZQ_SIZE; i += GBLOCKS * 256) {
        int bb = i >> 18;
        int c = (i >> 10) & 255;
        int hw = i & 1023;
        int n = (bb << 10) | hw;
        float q = e[(size_t)fidx[n] * C_DIM + c];
        float zv = z[i];
        zq[i] = q;
        float d = q - zv;
        s = fmaf(d, d, s);
    }
    #pragma unroll
    for (int off = 32; off; off >>= 1) s += __shfl_xor(s, off, 64);
    __shared__ float wsum[4];
    int lane = threadIdx.x & 63, w = threadIdx.x >> 6;
    if (lane == 0) wsum[w] = s;
    __syncthreads();
    if (threadIdx.x == 0) lpart[blockIdx.x] = wsum[0] + wsum[1] + wsum[2] + wsum[3];
}

__global__ __launch_bounds__(256) void k_loss(const float* __restrict__ lpart,
                                              float* __restrict__ out_loss) {
    float s = 0.0f;
    for (int i = threadIdx.x; i < GBLOCKS; i += 256) s += lpart[i];
    #pragma unroll
    for (int off = 32; off; off >>= 1) s += __shfl_xor(s, off, 64);
    __shared__ float wsum[4];
    int lane = threadIdx.x & 63, w = threadIdx.x >> 6;
    if (lane == 0) wsum[w] = s;
    __syncthreads();
    if (threadIdx.x == 0)
        out_loss[0] = (wsum[0] + wsum[1] + wsum[2] + wsum[3]) * (1.25f / (float)ZQ_SIZE);
}

extern "C" void kernel_launch(void* const* d_in, const int* in_sizes, int n_in,
                              void* d_out, int out_size, void* d_ws, size_t ws_size,
                              hipStream_t stream) {
    const float* z = (const float*)d_in[0];
    const float* e = (const float*)d_in[1];
    float* out = (float*)d_out;
    float* ws = (float*)d_ws;

    float* enorm1 = ws + WS_ENORM;
    u32* cnt = (u32*)(ws + WS_CNT);
    u64* packed = (u64*)(ws + WS_PACKED);
    int* fidx = (int*)(ws + WS_FIDX);
    float* lpart = ws + WS_LPART;
    uint2* list = (uint2*)(ws + WS_LIST);
    float* zt32 = ws + WS_ZT32;
    unsigned char* zt8 = (unsigned char*)(ws + WS_ZT8);
    unsigned char* eb8 = (unsigned char*)(ws + WS_EB8);

    hipMemsetAsync(cnt, 0, sizeof(u32), stream);
    hipMemsetAsync(packed, 0xFF, (size_t)N_TOT * sizeof(u64), stream);

    k_prep_e<<<dim3(K_DIM / 4), dim3(256), 0, stream>>>(e, eb8, enorm1);
    k_prep_z<<<dim3(2048), dim3(256), 0, stream>>>(z, zt32, zt8);
    k_screen<<<dim3(512), dim3(256), 0, stream>>>(zt8, eb8, enorm1, cnt, list);
    k_exact<<<dim3(1024), dim3(256), 0, stream>>>(zt32, e, enorm1, cnt, list, packed);
    k_fin<<<dim3(64), dim3(256), 0, stream>>>(packed, fidx, out + IDX_OFF);
    k_gather<<<dim3(GBLOCKS), dim3(256), 0, stream>>>(z, e, fidx, out, lpart);
    k_loss<<<dim3(1), dim3(256), 0, stream>>>(lpart, out + LOSS_OFF);
}